// Round 3
// baseline (1000.172 us; speedup 1.0000x reference)
//
#include <hip/hip_runtime.h>
#include <hip/hip_bf16.h>

// Problem constants (from reference): N=262144, NS=8, C=32, S=8 -> C/S=4
#define NPTS   262144
#define NSAMP  8
#define NPAIR  (NPTS * NSAMP)           // 2097152
#define EPSV   1e-5f
#define INVCNT (1.0f / (float)NPAIR)
#define GSTAT  1024                      // grid for stat kernels (partials rows)

typedef __hip_bfloat16 bf16;

template <typename T> __device__ __forceinline__ float cvt(T v);
template <> __device__ __forceinline__ float cvt<float>(float v) { return v; }
template <> __device__ __forceinline__ float cvt<bf16>(bf16 v) { return __bfloat162float(v); }

template <typename T> __device__ __forceinline__ T f2t(float v);
template <> __device__ __forceinline__ float f2t<float>(float v) { return v; }
template <> __device__ __forceinline__ bf16  f2t<bf16>(float v)  { return __float2bfloat16(v); }

// ---------------------------------------------------------------------------
// Detector: decide whether float inputs are bf16 (flag=0) or fp32 (flag=1).
// For bf16 data, the LOW half-word of each 32-bit word is a bf16 value of
// N(0,1) -> exponent field in [110,132] ~always. For fp32 data those bits are
// pure mantissa noise -> ~9% land in range. Threshold at 128/256.
// ---------------------------------------------------------------------------
__global__ void k_detect(const unsigned int* __restrict__ xw, int* __restrict__ flag)
{
    if (threadIdx.x == 0 && blockIdx.x == 0) {
        int cnt = 0;
        for (int i = 0; i < 256; ++i) {
            const unsigned int w = xw[i];
            const unsigned int e = (w >> 7) & 0xFF;   // exponent of low bf16
            if (e >= 110 && e <= 132) ++cnt;
        }
        flag[0] = (cnt >= 128) ? 0 : 1;
    }
}

// ---------------------------------------------------------------------------
// K1: q,k,v = x @ W.T + b   (fp32 out). Layout: thread = (point-in-chunk, c).
// ---------------------------------------------------------------------------
template <typename T>
__global__ __launch_bounds__(256) void k_qkv(
    const T* __restrict__ x,
    const T* __restrict__ Wq, const T* __restrict__ bq,
    const T* __restrict__ Wk, const T* __restrict__ bk,
    const T* __restrict__ Wv, const T* __restrict__ bv,
    float* __restrict__ q, float* __restrict__ k, float* __restrict__ v,
    const int* __restrict__ flag, const int want)
{
    if (flag[0] != want) return;
    __shared__ float Wt[3][32][32];   // [which][j][c] (transposed: conflict-free)
    __shared__ float xs[8][32];
    const int t = threadIdx.x;
    for (int e = t; e < 1024; e += 256) {
        const int c = e >> 5, j = e & 31;
        Wt[0][j][c] = cvt<T>(Wq[e]);
        Wt[1][j][c] = cvt<T>(Wk[e]);
        Wt[2][j][c] = cvt<T>(Wv[e]);
    }
    __syncthreads();
    const int c = t & 31, pi = t >> 5;
    const float bqv = cvt<T>(bq[c]), bkv = cvt<T>(bk[c]), bvv = cvt<T>(bv[c]);
    const int base0 = blockIdx.x * 256;           // 256 points per block
    for (int it = 0; it < 32; ++it) {
        const int base = base0 + it * 8;          // 8 points per iteration
        __syncthreads();
        xs[t >> 5][t & 31] = cvt<T>(x[base * 32 + t]);
        __syncthreads();
        float aq = bqv, ak = bkv, av = bvv;
#pragma unroll
        for (int j = 0; j < 32; ++j) {
            const float xv = xs[pi][j];
            aq += Wt[0][j][c] * xv;
            ak += Wt[1][j][c] * xv;
            av += Wt[2][j][c] * xv;
        }
        const int o = (base + pi) * 32 + c;
        q[o] = aq; k[o] = ak; v[o] = av;
    }
}

// ---------------------------------------------------------------------------
// K2: pr1 = (p[idx]-p) @ Wp1.T + bp1 (store), BN1 partial sums (3 ch, pad 8)
// Partial row layout: [0..2] sum, [8..10] sumsq, stride 16.
// ---------------------------------------------------------------------------
template <typename T>
__global__ __launch_bounds__(256) void k_pr1(
    const T* __restrict__ p, const int* __restrict__ idx,
    const T* __restrict__ Wp1, const T* __restrict__ bp1,
    float* __restrict__ pr1, float* __restrict__ P1,
    const int* __restrict__ flag, const int want)
{
    if (flag[0] != want) return;
    float W[3][3], B[3];
#pragma unroll
    for (int a = 0; a < 3; ++a) {
        B[a] = cvt<T>(bp1[a]);
#pragma unroll
        for (int d = 0; d < 3; ++d) W[a][d] = cvt<T>(Wp1[a * 3 + d]);
    }
    const int t = threadIdx.x;
    const int base = blockIdx.x * 2048;           // 2048 pairs per block
    float s[3] = {0.f, 0.f, 0.f}, ss[3] = {0.f, 0.f, 0.f};
    for (int it = 0; it < 2048; it += 256) {
        const int pid = base + it + t;
        const int i = pid >> 3;
        const int nj = idx[pid];
        const float d0 = cvt<T>(p[nj * 3 + 0]) - cvt<T>(p[i * 3 + 0]);
        const float d1 = cvt<T>(p[nj * 3 + 1]) - cvt<T>(p[i * 3 + 1]);
        const float d2 = cvt<T>(p[nj * 3 + 2]) - cvt<T>(p[i * 3 + 2]);
#pragma unroll
        for (int a = 0; a < 3; ++a) {
            const float r = W[a][0] * d0 + W[a][1] * d1 + W[a][2] * d2 + B[a];
            pr1[pid * 3 + a] = r;
            s[a] += r; ss[a] += r * r;
        }
    }
#pragma unroll
    for (int o = 32; o > 0; o >>= 1) {
#pragma unroll
        for (int a = 0; a < 3; ++a) { s[a] += __shfl_down(s[a], o); ss[a] += __shfl_down(ss[a], o); }
    }
    __shared__ float red[4][16];
    const int wid = t >> 6, lane = t & 63;
    if (lane == 0) {
#pragma unroll
        for (int u = 0; u < 16; ++u) red[wid][u] = 0.f;
#pragma unroll
        for (int a = 0; a < 3; ++a) { red[wid][a] = s[a]; red[wid][8 + a] = ss[a]; }
    }
    __syncthreads();
    if (t < 16) P1[blockIdx.x * 16 + t] = red[0][t] + red[1][t] + red[2][t] + red[3][t];
}

// ---------------------------------------------------------------------------
// Finalize: reduce partials, coef a = g*rsqrt(var+eps), c = b - a*mean
// Partial stride = 2*NP; sums at [0..NC), sumsq at [NP..NP+NC)
// ---------------------------------------------------------------------------
template <typename T, int NC_, int NP_>
__global__ __launch_bounds__(64) void k_fin(
    const float* __restrict__ P, const int nblocks,
    const T* __restrict__ g, const T* __restrict__ b,
    float* __restrict__ A, float* __restrict__ Cc,
    const int* __restrict__ flag, const int want)
{
    if (flag[0] != want) return;
    const int t = threadIdx.x;
    float acc = 0.f;
    if (t < 2 * NP_) {
        for (int bb = 0; bb < nblocks; ++bb) acc += P[bb * 2 * NP_ + t];
    }
    __shared__ float tot[64];
    if (t < 2 * NP_) tot[t] = acc;
    __syncthreads();
    if (t < NC_) {
        const float m = tot[t] * INVCNT;
        const float var = tot[NP_ + t] * INVCNT - m * m;
        const float a = cvt<T>(g[t]) * rsqrtf(var + EPSV);
        A[t] = a;
        Cc[t] = cvt<T>(b[t]) - a * m;
    }
}

// ---------------------------------------------------------------------------
// K4: BN2 partials over w_pre = k[idx] - q + relu(bn1(pr1)) @ Wp2.T + bp2
// Layout: c = t&31 (channel-parallel), 8 pairs per 256-thread iteration.
// Partial row: [c] sum, [32+c] sumsq, stride 64.
// ---------------------------------------------------------------------------
template <typename T>
__global__ __launch_bounds__(256) void k_bn2stat(
    const int* __restrict__ idx, const float* __restrict__ pr1,
    const float* __restrict__ q, const float* __restrict__ k,
    const T* __restrict__ Wp2, const T* __restrict__ bp2,
    const float* __restrict__ coef, float* __restrict__ P2,
    const int* __restrict__ flag, const int want)
{
    if (flag[0] != want) return;
    const int t = threadIdx.x;
    const int c = t & 31;
    const float a10 = coef[0], a11 = coef[1], a12 = coef[2];
    const float c10 = coef[8], c11 = coef[9], c12 = coef[10];
    const float w0 = cvt<T>(Wp2[c * 3 + 0]), w1 = cvt<T>(Wp2[c * 3 + 1]), w2 = cvt<T>(Wp2[c * 3 + 2]);
    const float bb = cvt<T>(bp2[c]);
    float s = 0.f, ss = 0.f;
    const int base = blockIdx.x * 2048;
    for (int it = 0; it < 2048; it += 8) {
        const int pid = base + it + (t >> 5);
        const int i = pid >> 3;
        const int nj = idx[pid];
        const float h0 = fmaxf(a10 * pr1[pid * 3 + 0] + c10, 0.f);
        const float h1 = fmaxf(a11 * pr1[pid * 3 + 1] + c11, 0.f);
        const float h2 = fmaxf(a12 * pr1[pid * 3 + 2] + c12, 0.f);
        const float pr2 = w0 * h0 + w1 * h1 + w2 * h2 + bb;
        const float wp = k[nj * 32 + c] - q[i * 32 + c] + pr2;
        s += wp; ss += wp * wp;
    }
    s += __shfl_down(s, 32); ss += __shfl_down(ss, 32);
    __shared__ float red[4][64];
    const int wid = t >> 6, lane = t & 63;
    if (lane < 32) { red[wid][lane] = s; red[wid][32 + lane] = ss; }
    __syncthreads();
    if (t < 64) P2[blockIdx.x * 64 + t] = red[0][t] + red[1][t] + red[2][t] + red[3][t];
}

// ---------------------------------------------------------------------------
// K6: w1 = relu(bn2(w_pre)) @ Ww1.T + bww1 (store), BN3 partials (4 ch)
// Thread-per-pair. Partial row: [0..3] sum, [4..7] sumsq, stride 8.
// ---------------------------------------------------------------------------
template <typename T>
__global__ __launch_bounds__(256) void k_w1(
    const int* __restrict__ idx, const float* __restrict__ pr1,
    const float* __restrict__ q, const float* __restrict__ k,
    const T* __restrict__ Wp2, const T* __restrict__ bp2,
    const T* __restrict__ Ww1, const T* __restrict__ bww1,
    const float* __restrict__ coef, float* __restrict__ w1out, float* __restrict__ P3,
    const int* __restrict__ flag, const int want)
{
    if (flag[0] != want) return;
    __shared__ float sWp2[32][3], sbp2[32], sW1[4][32], sb1[4], sa2[32], sc2[32];
    const int t = threadIdx.x;
    if (t < 32) {
        sWp2[t][0] = cvt<T>(Wp2[t * 3 + 0]);
        sWp2[t][1] = cvt<T>(Wp2[t * 3 + 1]);
        sWp2[t][2] = cvt<T>(Wp2[t * 3 + 2]);
        sbp2[t] = cvt<T>(bp2[t]);
        sa2[t] = coef[16 + t];
        sc2[t] = coef[48 + t];
    }
    if (t < 4) sb1[t] = cvt<T>(bww1[t]);
    if (t < 128) sW1[t >> 5][t & 31] = cvt<T>(Ww1[t]);
    __syncthreads();
    const float a10 = coef[0], a11 = coef[1], a12 = coef[2];
    const float c10 = coef[8], c11 = coef[9], c12 = coef[10];
    float s[4] = {0.f, 0.f, 0.f, 0.f}, ss[4] = {0.f, 0.f, 0.f, 0.f};
    const int base = blockIdx.x * 2048;
    for (int it = 0; it < 2048; it += 256) {
        const int pid = base + it + t;
        const int i = pid >> 3;
        const int nj = idx[pid];
        const float h0 = fmaxf(a10 * pr1[pid * 3 + 0] + c10, 0.f);
        const float h1 = fmaxf(a11 * pr1[pid * 3 + 1] + c11, 0.f);
        const float h2 = fmaxf(a12 * pr1[pid * 3 + 2] + c12, 0.f);
        float acc[4] = {sb1[0], sb1[1], sb1[2], sb1[3]};
        const float* krow = k + nj * 32;
        const float* qrow = q + i * 32;
#pragma unroll
        for (int cc = 0; cc < 32; ++cc) {
            const float pr2 = sWp2[cc][0] * h0 + sWp2[cc][1] * h1 + sWp2[cc][2] * h2 + sbp2[cc];
            const float wp = krow[cc] - qrow[cc] + pr2;
            const float hh = fmaxf(sa2[cc] * wp + sc2[cc], 0.f);
            acc[0] += sW1[0][cc] * hh;
            acc[1] += sW1[1][cc] * hh;
            acc[2] += sW1[2][cc] * hh;
            acc[3] += sW1[3][cc] * hh;
        }
#pragma unroll
        for (int u = 0; u < 4; ++u) {
            w1out[pid * 4 + u] = acc[u];
            s[u] += acc[u]; ss[u] += acc[u] * acc[u];
        }
    }
#pragma unroll
    for (int o = 32; o > 0; o >>= 1) {
#pragma unroll
        for (int u = 0; u < 4; ++u) { s[u] += __shfl_down(s[u], o); ss[u] += __shfl_down(ss[u], o); }
    }
    __shared__ float red[4][8];
    const int wid = t >> 6, lane = t & 63;
    if (lane == 0) {
#pragma unroll
        for (int u = 0; u < 4; ++u) { red[wid][u] = s[u]; red[wid][4 + u] = ss[u]; }
    }
    __syncthreads();
    if (t < 8) P3[blockIdx.x * 8 + t] = red[0][t] + red[1][t] + red[2][t] + red[3][t];
}

// ---------------------------------------------------------------------------
// K8: logits = relu(bn3(w1)) @ Ww2.T + bww2; softmax over ns;
//     out[i,c] = sum_j (v[idx]+pr2) * wsoft[j, c&3]
// Layout: thread = (point-in-chunk, c). Output dtype = input dtype (hedge).
// ---------------------------------------------------------------------------
template <typename T>
__global__ __launch_bounds__(256) void k_out(
    const int* __restrict__ idx, const float* __restrict__ pr1,
    const float* __restrict__ v, const float* __restrict__ w1in,
    const T* __restrict__ Wp2, const T* __restrict__ bp2,
    const T* __restrict__ Ww2, const T* __restrict__ bww2,
    const float* __restrict__ coef, T* __restrict__ out,
    const int* __restrict__ flag, const int want)
{
    if (flag[0] != want) return;
    const int t = threadIdx.x;
    const int c = t & 31, pi = t >> 5;
    const float a10 = coef[0], a11 = coef[1], a12 = coef[2];
    const float c10 = coef[8], c11 = coef[9], c12 = coef[10];
    const float wA = cvt<T>(Wp2[c * 3 + 0]), wB = cvt<T>(Wp2[c * 3 + 1]), wC = cvt<T>(Wp2[c * 3 + 2]);
    const float bb = cvt<T>(bp2[c]);
    const int tq = c & 3;
    float a3[4], c3[4], W2r[4];
#pragma unroll
    for (int u = 0; u < 4; ++u) {
        a3[u] = coef[80 + u]; c3[u] = coef[88 + u];
        W2r[u] = cvt<T>(Ww2[tq * 4 + u]);
    }
    const float b2r = cvt<T>(bww2[tq]);
    const int base0 = blockIdx.x * 256;
    for (int it = 0; it < 32; ++it) {
        const int i = base0 + it * 8 + pi;
        float lg[8];
#pragma unroll
        for (int j = 0; j < 8; ++j) {
            const float* wr = w1in + (i * 8 + j) * 4;
            float l = b2r;
#pragma unroll
            for (int u = 0; u < 4; ++u) l += W2r[u] * fmaxf(a3[u] * wr[u] + c3[u], 0.f);
            lg[j] = l;
        }
        float m = lg[0];
#pragma unroll
        for (int j = 1; j < 8; ++j) m = fmaxf(m, lg[j]);
        float sum = 0.f;
#pragma unroll
        for (int j = 0; j < 8; ++j) { lg[j] = __expf(lg[j] - m); sum += lg[j]; }
        const float inv = 1.f / sum;
        float acc = 0.f;
#pragma unroll
        for (int j = 0; j < 8; ++j) {
            const int pid = i * 8 + j;
            const int nj = idx[pid];
            const float h0 = fmaxf(a10 * pr1[pid * 3 + 0] + c10, 0.f);
            const float h1 = fmaxf(a11 * pr1[pid * 3 + 1] + c11, 0.f);
            const float h2 = fmaxf(a12 * pr1[pid * 3 + 2] + c12, 0.f);
            const float pr2 = wA * h0 + wB * h1 + wC * h2 + bb;
            acc += (v[nj * 32 + c] + pr2) * (lg[j] * inv);
        }
        out[i * 32 + c] = f2t<T>(acc);
    }
}

// ---------------------------------------------------------------------------
template <typename T>
static void launch_pipeline(void* const* d_in, void* d_out, float* ws,
                            int* flag, const int want, hipStream_t stream)
{
    const T*   p    = (const T*)d_in[0];
    const T*   x    = (const T*)d_in[1];
    const int* idx  = (const int*)d_in[2];
    const T*   Wq   = (const T*)d_in[3];
    const T*   bq   = (const T*)d_in[4];
    const T*   Wk   = (const T*)d_in[5];
    const T*   bk   = (const T*)d_in[6];
    const T*   Wv   = (const T*)d_in[7];
    const T*   bv   = (const T*)d_in[8];
    const T*   Wp1  = (const T*)d_in[9];
    const T*   bp1  = (const T*)d_in[10];
    const T*   gp   = (const T*)d_in[11];
    const T*   bp   = (const T*)d_in[12];
    const T*   Wp2  = (const T*)d_in[13];
    const T*   bp2  = (const T*)d_in[14];
    const T*   gw1  = (const T*)d_in[15];
    const T*   bw1  = (const T*)d_in[16];
    const T*   Ww1  = (const T*)d_in[17];
    const T*   bww1 = (const T*)d_in[18];
    const T*   gw2  = (const T*)d_in[19];
    const T*   bw2  = (const T*)d_in[20];
    const T*   Ww2  = (const T*)d_in[21];
    const T*   bww2 = (const T*)d_in[22];
    T* out = (T*)d_out;

    // ws layout: [0] flag (+pad), [16..112) coef, [128..) partials, big arrays after 131072
    float* coef = ws + 16;                    // 96 floats
    float* P1   = ws + 128;                   // GSTAT*16
    float* P2   = P1 + GSTAT * 16;            // GSTAT*64
    float* P3   = P2 + GSTAT * 64;            // GSTAT*8
    float* q    = ws + 131072;                // NPTS*32
    float* k    = q  + (size_t)NPTS * 32;     // NPTS*32
    float* v    = k  + (size_t)NPTS * 32;     // NPTS*32
    float* pr1  = v  + (size_t)NPTS * 32;     // NPAIR*3
    float* w1   = pr1 + (size_t)NPAIR * 3;    // NPAIR*4   (total ~160 MB)

    k_qkv<T><<<1024, 256, 0, stream>>>(x, Wq, bq, Wk, bk, Wv, bv, q, k, v, flag, want);
    k_pr1<T><<<GSTAT, 256, 0, stream>>>(p, idx, Wp1, bp1, pr1, P1, flag, want);
    k_fin<T, 3, 8><<<1, 64, 0, stream>>>(P1, GSTAT, gp, bp, coef + 0, coef + 8, flag, want);
    k_bn2stat<T><<<GSTAT, 256, 0, stream>>>(idx, pr1, q, k, Wp2, bp2, coef, P2, flag, want);
    k_fin<T, 32, 32><<<1, 64, 0, stream>>>(P2, GSTAT, gw1, bw1, coef + 16, coef + 48, flag, want);
    k_w1<T><<<GSTAT, 256, 0, stream>>>(idx, pr1, q, k, Wp2, bp2, Ww1, bww1, coef, w1, P3, flag, want);
    k_fin<T, 4, 4><<<1, 64, 0, stream>>>(P3, GSTAT, gw2, bw2, coef + 80, coef + 88, flag, want);
    k_out<T><<<1024, 256, 0, stream>>>(idx, pr1, v, w1, Wp2, bp2, Ww2, bww2, coef, out, flag, want);
}

extern "C" void kernel_launch(void* const* d_in, const int* in_sizes, int n_in,
                              void* d_out, int out_size, void* d_ws, size_t ws_size,
                              hipStream_t stream)
{
    float* ws = (float*)d_ws;
    int* flag = (int*)ws;   // ws[0]

    k_detect<<<1, 64, 0, stream>>>((const unsigned int*)d_in[1], flag);
    launch_pipeline<bf16>(d_in, d_out, ws, flag, 0, stream);    // bf16 in -> bf16 out
    launch_pipeline<float>(d_in, d_out, ws, flag, 1, stream);   // fp32 in -> fp32 out
}

// Round 4
// 519.023 us; speedup vs baseline: 1.9270x; 1.9270x over previous
//
#include <hip/hip_runtime.h>
#include <hip/hip_bf16.h>

// Problem constants (from reference): N=262144, NS=8, C=32, S=8 -> C/S=4
#define NPTS   262144
#define NSAMP  8
#define NPAIR  (NPTS * NSAMP)           // 2097152
#define EPSV   1e-5f
#define INVCNT (1.0f / (float)NPAIR)
#define GSTAT  1024                      // grid for stat kernels (partials rows)

typedef __hip_bfloat16 bf16;

template <typename T> __device__ __forceinline__ float cvt(T v);
template <> __device__ __forceinline__ float cvt<float>(float v) { return v; }
template <> __device__ __forceinline__ float cvt<bf16>(bf16 v) { return __bfloat162float(v); }

template <typename T> __device__ __forceinline__ T f2t(float v);
template <> __device__ __forceinline__ float f2t<float>(float v) { return v; }
template <> __device__ __forceinline__ bf16  f2t<bf16>(float v)  { return __float2bfloat16(v); }

// ---------------------------------------------------------------------------
// Detector: decide whether float inputs are bf16 (flag=0) or fp32 (flag=1).
// ---------------------------------------------------------------------------
__global__ void k_detect(const unsigned int* __restrict__ xw, int* __restrict__ flag)
{
    if (threadIdx.x == 0 && blockIdx.x == 0) {
        int cnt = 0;
        for (int i = 0; i < 256; ++i) {
            const unsigned int w = xw[i];
            const unsigned int e = (w >> 7) & 0xFF;   // exponent of low bf16
            if (e >= 110 && e <= 132) ++cnt;
        }
        flag[0] = (cnt >= 128) ? 0 : 1;
    }
}

// ---------------------------------------------------------------------------
// K1: q,k,v = x @ W.T + b   (fp32 out). Layout: thread = (point-in-chunk, c).
// ---------------------------------------------------------------------------
template <typename T>
__global__ __launch_bounds__(256) void k_qkv(
    const T* __restrict__ x,
    const T* __restrict__ Wq, const T* __restrict__ bq,
    const T* __restrict__ Wk, const T* __restrict__ bk,
    const T* __restrict__ Wv, const T* __restrict__ bv,
    float* __restrict__ q, float* __restrict__ k, float* __restrict__ v,
    const int* __restrict__ flag, const int want)
{
    if (flag[0] != want) return;
    __shared__ float Wt[3][32][32];   // [which][j][c] (transposed: conflict-free)
    __shared__ float xs[8][32];
    const int t = threadIdx.x;
    for (int e = t; e < 1024; e += 256) {
        const int c = e >> 5, j = e & 31;
        Wt[0][j][c] = cvt<T>(Wq[e]);
        Wt[1][j][c] = cvt<T>(Wk[e]);
        Wt[2][j][c] = cvt<T>(Wv[e]);
    }
    __syncthreads();
    const int c = t & 31, pi = t >> 5;
    const float bqv = cvt<T>(bq[c]), bkv = cvt<T>(bk[c]), bvv = cvt<T>(bv[c]);
    const int base0 = blockIdx.x * 256;           // 256 points per block
    for (int it = 0; it < 32; ++it) {
        const int base = base0 + it * 8;          // 8 points per iteration
        __syncthreads();
        xs[t >> 5][t & 31] = cvt<T>(x[base * 32 + t]);
        __syncthreads();
        float aq = bqv, ak = bkv, av = bvv;
#pragma unroll
        for (int j = 0; j < 32; ++j) {
            const float xv = xs[pi][j];
            aq += Wt[0][j][c] * xv;
            ak += Wt[1][j][c] * xv;
            av += Wt[2][j][c] * xv;
        }
        const int o = (base + pi) * 32 + c;
        q[o] = aq; k[o] = ak; v[o] = av;
    }
}

// ---------------------------------------------------------------------------
// K2: pr1 = (p[idx]-p) @ Wp1.T + bp1 (store), BN1 partial sums (3 ch, pad 8)
// Partial row layout: [0..2] sum, [8..10] sumsq, stride 16.
// ---------------------------------------------------------------------------
template <typename T>
__global__ __launch_bounds__(256) void k_pr1(
    const T* __restrict__ p, const int* __restrict__ idx,
    const T* __restrict__ Wp1, const T* __restrict__ bp1,
    float* __restrict__ pr1, float* __restrict__ P1,
    const int* __restrict__ flag, const int want)
{
    if (flag[0] != want) return;
    float W[3][3], B[3];
#pragma unroll
    for (int a = 0; a < 3; ++a) {
        B[a] = cvt<T>(bp1[a]);
#pragma unroll
        for (int d = 0; d < 3; ++d) W[a][d] = cvt<T>(Wp1[a * 3 + d]);
    }
    const int t = threadIdx.x;
    const int base = blockIdx.x * 2048;           // 2048 pairs per block
    float s[3] = {0.f, 0.f, 0.f}, ss[3] = {0.f, 0.f, 0.f};
    for (int it = 0; it < 2048; it += 256) {
        const int pid = base + it + t;
        const int i = pid >> 3;
        const int nj = idx[pid];
        const float d0 = cvt<T>(p[nj * 3 + 0]) - cvt<T>(p[i * 3 + 0]);
        const float d1 = cvt<T>(p[nj * 3 + 1]) - cvt<T>(p[i * 3 + 1]);
        const float d2 = cvt<T>(p[nj * 3 + 2]) - cvt<T>(p[i * 3 + 2]);
#pragma unroll
        for (int a = 0; a < 3; ++a) {
            const float r = W[a][0] * d0 + W[a][1] * d1 + W[a][2] * d2 + B[a];
            pr1[pid * 3 + a] = r;
            s[a] += r; ss[a] += r * r;
        }
    }
#pragma unroll
    for (int o = 32; o > 0; o >>= 1) {
#pragma unroll
        for (int a = 0; a < 3; ++a) { s[a] += __shfl_down(s[a], o); ss[a] += __shfl_down(ss[a], o); }
    }
    __shared__ float red[4][16];
    const int wid = t >> 6, lane = t & 63;
    if (lane == 0) {
#pragma unroll
        for (int u = 0; u < 16; ++u) red[wid][u] = 0.f;
#pragma unroll
        for (int a = 0; a < 3; ++a) { red[wid][a] = s[a]; red[wid][8 + a] = ss[a]; }
    }
    __syncthreads();
    if (t < 16) P1[blockIdx.x * 16 + t] = red[0][t] + red[1][t] + red[2][t] + red[3][t];
}

// ---------------------------------------------------------------------------
// Finalize: reduce GSTAT partial rows (2*NP columns), coef a/c.
// PARALLEL version: 1024 threads; thread = (column c, row-group g);
// grid-stride over rows; LDS tree-reduce over row-groups.
// Round-3 profile: old 64-thread serial loop was 250 us/launch (586 cyc/iter,
// latency-bound, 1 CU). This is ~16 parallel load rounds across 16 waves.
// ---------------------------------------------------------------------------
template <typename T, int NC_, int NP_>
__global__ __launch_bounds__(1024) void k_fin(
    const float* __restrict__ P, const int nblocks,
    const T* __restrict__ g, const T* __restrict__ b,
    float* __restrict__ A, float* __restrict__ Cc,
    const int* __restrict__ flag, const int want)
{
    if (flag[0] != want) return;
    constexpr int COLS = 2 * NP_;
    constexpr int GRP  = 1024 / COLS;
    const int t = threadIdx.x;
    const int c = t % COLS;
    const int gi = t / COLS;
    float acc = 0.f;
    for (int r = gi; r < nblocks; r += GRP) acc += P[r * COLS + c];
    __shared__ float red[1024];
    red[t] = acc;
    __syncthreads();
#pragma unroll
    for (int s = GRP >> 1; s > 0; s >>= 1) {
        if (gi < s) red[t] += red[t + s * COLS];
        __syncthreads();
    }
    if (t < NC_) {
        const float m = red[t] * INVCNT;
        const float var = red[NP_ + t] * INVCNT - m * m;
        const float a = cvt<T>(g[t]) * rsqrtf(var + EPSV);
        A[t] = a;
        Cc[t] = cvt<T>(b[t]) - a * m;
    }
}

// ---------------------------------------------------------------------------
// K4: BN2 partials over w_pre = k[idx] - q + relu(bn1(pr1)) @ Wp2.T + bp2
// Layout: c = t&31 (channel-parallel), 8 pairs per 256-thread iteration.
// Partial row: [c] sum, [32+c] sumsq, stride 64.
// ---------------------------------------------------------------------------
template <typename T>
__global__ __launch_bounds__(256) void k_bn2stat(
    const int* __restrict__ idx, const float* __restrict__ pr1,
    const float* __restrict__ q, const float* __restrict__ k,
    const T* __restrict__ Wp2, const T* __restrict__ bp2,
    const float* __restrict__ coef, float* __restrict__ P2,
    const int* __restrict__ flag, const int want)
{
    if (flag[0] != want) return;
    const int t = threadIdx.x;
    const int c = t & 31;
    const float a10 = coef[0], a11 = coef[1], a12 = coef[2];
    const float c10 = coef[8], c11 = coef[9], c12 = coef[10];
    const float w0 = cvt<T>(Wp2[c * 3 + 0]), w1 = cvt<T>(Wp2[c * 3 + 1]), w2 = cvt<T>(Wp2[c * 3 + 2]);
    const float bb = cvt<T>(bp2[c]);
    float s = 0.f, ss = 0.f;
    const int base = blockIdx.x * 2048;
    for (int it = 0; it < 2048; it += 8) {
        const int pid = base + it + (t >> 5);
        const int i = pid >> 3;
        const int nj = idx[pid];
        const float h0 = fmaxf(a10 * pr1[pid * 3 + 0] + c10, 0.f);
        const float h1 = fmaxf(a11 * pr1[pid * 3 + 1] + c11, 0.f);
        const float h2 = fmaxf(a12 * pr1[pid * 3 + 2] + c12, 0.f);
        const float pr2 = w0 * h0 + w1 * h1 + w2 * h2 + bb;
        const float wp = k[nj * 32 + c] - q[i * 32 + c] + pr2;
        s += wp; ss += wp * wp;
    }
    s += __shfl_down(s, 32); ss += __shfl_down(ss, 32);
    __shared__ float red[4][64];
    const int wid = t >> 6, lane = t & 63;
    if (lane < 32) { red[wid][lane] = s; red[wid][32 + lane] = ss; }
    __syncthreads();
    if (t < 64) P2[blockIdx.x * 64 + t] = red[0][t] + red[1][t] + red[2][t] + red[3][t];
}

// ---------------------------------------------------------------------------
// K6: w1 = relu(bn2(w_pre)) @ Ww1.T + bww1 (store), BN3 partials (4 ch)
// Thread-per-pair. Partial row: [0..3] sum, [4..7] sumsq, stride 8.
// ---------------------------------------------------------------------------
template <typename T>
__global__ __launch_bounds__(256) void k_w1(
    const int* __restrict__ idx, const float* __restrict__ pr1,
    const float* __restrict__ q, const float* __restrict__ k,
    const T* __restrict__ Wp2, const T* __restrict__ bp2,
    const T* __restrict__ Ww1, const T* __restrict__ bww1,
    const float* __restrict__ coef, float* __restrict__ w1out, float* __restrict__ P3,
    const int* __restrict__ flag, const int want)
{
    if (flag[0] != want) return;
    __shared__ float sWp2[32][3], sbp2[32], sW1[4][32], sb1[4], sa2[32], sc2[32];
    const int t = threadIdx.x;
    if (t < 32) {
        sWp2[t][0] = cvt<T>(Wp2[t * 3 + 0]);
        sWp2[t][1] = cvt<T>(Wp2[t * 3 + 1]);
        sWp2[t][2] = cvt<T>(Wp2[t * 3 + 2]);
        sbp2[t] = cvt<T>(bp2[t]);
        sa2[t] = coef[16 + t];
        sc2[t] = coef[48 + t];
    }
    if (t < 4) sb1[t] = cvt<T>(bww1[t]);
    if (t < 128) sW1[t >> 5][t & 31] = cvt<T>(Ww1[t]);
    __syncthreads();
    const float a10 = coef[0], a11 = coef[1], a12 = coef[2];
    const float c10 = coef[8], c11 = coef[9], c12 = coef[10];
    float s[4] = {0.f, 0.f, 0.f, 0.f}, ss[4] = {0.f, 0.f, 0.f, 0.f};
    const int base = blockIdx.x * 2048;
    for (int it = 0; it < 2048; it += 256) {
        const int pid = base + it + t;
        const int i = pid >> 3;
        const int nj = idx[pid];
        const float h0 = fmaxf(a10 * pr1[pid * 3 + 0] + c10, 0.f);
        const float h1 = fmaxf(a11 * pr1[pid * 3 + 1] + c11, 0.f);
        const float h2 = fmaxf(a12 * pr1[pid * 3 + 2] + c12, 0.f);
        float acc[4] = {sb1[0], sb1[1], sb1[2], sb1[3]};
        const float* krow = k + nj * 32;
        const float* qrow = q + i * 32;
#pragma unroll
        for (int cc = 0; cc < 32; ++cc) {
            const float pr2 = sWp2[cc][0] * h0 + sWp2[cc][1] * h1 + sWp2[cc][2] * h2 + sbp2[cc];
            const float wp = krow[cc] - qrow[cc] + pr2;
            const float hh = fmaxf(sa2[cc] * wp + sc2[cc], 0.f);
            acc[0] += sW1[0][cc] * hh;
            acc[1] += sW1[1][cc] * hh;
            acc[2] += sW1[2][cc] * hh;
            acc[3] += sW1[3][cc] * hh;
        }
#pragma unroll
        for (int u = 0; u < 4; ++u) {
            w1out[pid * 4 + u] = acc[u];
            s[u] += acc[u]; ss[u] += acc[u] * acc[u];
        }
    }
#pragma unroll
    for (int o = 32; o > 0; o >>= 1) {
#pragma unroll
        for (int u = 0; u < 4; ++u) { s[u] += __shfl_down(s[u], o); ss[u] += __shfl_down(ss[u], o); }
    }
    __shared__ float red[4][8];
    const int wid = t >> 6, lane = t & 63;
    if (lane == 0) {
#pragma unroll
        for (int u = 0; u < 4; ++u) { red[wid][u] = s[u]; red[wid][4 + u] = ss[u]; }
    }
    __syncthreads();
    if (t < 8) P3[blockIdx.x * 8 + t] = red[0][t] + red[1][t] + red[2][t] + red[3][t];
}

// ---------------------------------------------------------------------------
// K8: logits = relu(bn3(w1)) @ Ww2.T + bww2; softmax over ns;
//     out[i,c] = sum_j (v[idx]+pr2) * wsoft[j, c&3]
// ---------------------------------------------------------------------------
template <typename T>
__global__ __launch_bounds__(256) void k_out(
    const int* __restrict__ idx, const float* __restrict__ pr1,
    const float* __restrict__ v, const float* __restrict__ w1in,
    const T* __restrict__ Wp2, const T* __restrict__ bp2,
    const T* __restrict__ Ww2, const T* __restrict__ bww2,
    const float* __restrict__ coef, T* __restrict__ out,
    const int* __restrict__ flag, const int want)
{
    if (flag[0] != want) return;
    const int t = threadIdx.x;
    const int c = t & 31, pi = t >> 5;
    const float a10 = coef[0], a11 = coef[1], a12 = coef[2];
    const float c10 = coef[8], c11 = coef[9], c12 = coef[10];
    const float wA = cvt<T>(Wp2[c * 3 + 0]), wB = cvt<T>(Wp2[c * 3 + 1]), wC = cvt<T>(Wp2[c * 3 + 2]);
    const float bb = cvt<T>(bp2[c]);
    const int tq = c & 3;
    float a3[4], c3[4], W2r[4];
#pragma unroll
    for (int u = 0; u < 4; ++u) {
        a3[u] = coef[80 + u]; c3[u] = coef[88 + u];
        W2r[u] = cvt<T>(Ww2[tq * 4 + u]);
    }
    const float b2r = cvt<T>(bww2[tq]);
    const int base0 = blockIdx.x * 256;
    for (int it = 0; it < 32; ++it) {
        const int i = base0 + it * 8 + pi;
        float lg[8];
#pragma unroll
        for (int j = 0; j < 8; ++j) {
            const float* wr = w1in + (i * 8 + j) * 4;
            float l = b2r;
#pragma unroll
            for (int u = 0; u < 4; ++u) l += W2r[u] * fmaxf(a3[u] * wr[u] + c3[u], 0.f);
            lg[j] = l;
        }
        float m = lg[0];
#pragma unroll
        for (int j = 1; j < 8; ++j) m = fmaxf(m, lg[j]);
        float sum = 0.f;
#pragma unroll
        for (int j = 0; j < 8; ++j) { lg[j] = __expf(lg[j] - m); sum += lg[j]; }
        const float inv = 1.f / sum;
        float acc = 0.f;
#pragma unroll
        for (int j = 0; j < 8; ++j) {
            const int pid = i * 8 + j;
            const int nj = idx[pid];
            const float h0 = fmaxf(a10 * pr1[pid * 3 + 0] + c10, 0.f);
            const float h1 = fmaxf(a11 * pr1[pid * 3 + 1] + c11, 0.f);
            const float h2 = fmaxf(a12 * pr1[pid * 3 + 2] + c12, 0.f);
            const float pr2 = wA * h0 + wB * h1 + wC * h2 + bb;
            acc += (v[nj * 32 + c] + pr2) * (lg[j] * inv);
        }
        out[i * 32 + c] = f2t<T>(acc);
    }
}

// ---------------------------------------------------------------------------
template <typename T>
static void launch_pipeline(void* const* d_in, void* d_out, float* ws,
                            int* flag, const int want, hipStream_t stream)
{
    const T*   p    = (const T*)d_in[0];
    const T*   x    = (const T*)d_in[1];
    const int* idx  = (const int*)d_in[2];
    const T*   Wq   = (const T*)d_in[3];
    const T*   bq   = (const T*)d_in[4];
    const T*   Wk   = (const T*)d_in[5];
    const T*   bk   = (const T*)d_in[6];
    const T*   Wv   = (const T*)d_in[7];
    const T*   bv   = (const T*)d_in[8];
    const T*   Wp1  = (const T*)d_in[9];
    const T*   bp1  = (const T*)d_in[10];
    const T*   gp   = (const T*)d_in[11];
    const T*   bp   = (const T*)d_in[12];
    const T*   Wp2  = (const T*)d_in[13];
    const T*   bp2  = (const T*)d_in[14];
    const T*   gw1  = (const T*)d_in[15];
    const T*   bw1  = (const T*)d_in[16];
    const T*   Ww1  = (const T*)d_in[17];
    const T*   bww1 = (const T*)d_in[18];
    const T*   gw2  = (const T*)d_in[19];
    const T*   bw2  = (const T*)d_in[20];
    const T*   Ww2  = (const T*)d_in[21];
    const T*   bww2 = (const T*)d_in[22];
    T* out = (T*)d_out;

    // ws layout: [0] flag (+pad), [16..112) coef, [128..) partials, big arrays after 131072
    float* coef = ws + 16;                    // 96 floats
    float* P1   = ws + 128;                   // GSTAT*16
    float* P2   = P1 + GSTAT * 16;            // GSTAT*64
    float* P3   = P2 + GSTAT * 64;            // GSTAT*8
    float* q    = ws + 131072;                // NPTS*32
    float* k    = q  + (size_t)NPTS * 32;     // NPTS*32
    float* v    = k  + (size_t)NPTS * 32;     // NPTS*32
    float* pr1  = v  + (size_t)NPTS * 32;     // NPAIR*3
    float* w1   = pr1 + (size_t)NPAIR * 3;    // NPAIR*4   (total ~160 MB)

    k_qkv<T><<<1024, 256, 0, stream>>>(x, Wq, bq, Wk, bk, Wv, bv, q, k, v, flag, want);
    k_pr1<T><<<GSTAT, 256, 0, stream>>>(p, idx, Wp1, bp1, pr1, P1, flag, want);
    k_fin<T, 3, 8><<<1, 1024, 0, stream>>>(P1, GSTAT, gp, bp, coef + 0, coef + 8, flag, want);
    k_bn2stat<T><<<GSTAT, 256, 0, stream>>>(idx, pr1, q, k, Wp2, bp2, coef, P2, flag, want);
    k_fin<T, 32, 32><<<1, 1024, 0, stream>>>(P2, GSTAT, gw1, bw1, coef + 16, coef + 48, flag, want);
    k_w1<T><<<GSTAT, 256, 0, stream>>>(idx, pr1, q, k, Wp2, bp2, Ww1, bww1, coef, w1, P3, flag, want);
    k_fin<T, 4, 4><<<1, 1024, 0, stream>>>(P3, GSTAT, gw2, bw2, coef + 80, coef + 88, flag, want);
    k_out<T><<<1024, 256, 0, stream>>>(idx, pr1, v, w1, Wp2, bp2, Ww2, bww2, coef, out, flag, want);
}

extern "C" void kernel_launch(void* const* d_in, const int* in_sizes, int n_in,
                              void* d_out, int out_size, void* d_ws, size_t ws_size,
                              hipStream_t stream)
{
    float* ws = (float*)d_ws;
    int* flag = (int*)ws;   // ws[0]

    k_detect<<<1, 64, 0, stream>>>((const unsigned int*)d_in[1], flag);
    launch_pipeline<bf16>(d_in, d_out, ws, flag, 0, stream);    // bf16 in -> bf16 out
    launch_pipeline<float>(d_in, d_out, ws, flag, 1, stream);   // fp32 in -> fp32 out
}